// Round 8
// baseline (1300.045 us; speedup 1.0000x reference)
//
#include <hip/hip_runtime.h>
#include <hip/hip_bf16.h>

#define AS1 __attribute__((address_space(1)))
#define AS3 __attribute__((address_space(3)))

typedef __bf16 bf16_t;
typedef __attribute__((ext_vector_type(8))) __bf16 bfrag;
typedef __attribute__((ext_vector_type(4))) __bf16 bf16x4;
typedef __attribute__((ext_vector_type(2))) __bf16 bf16x2;
typedef __attribute__((ext_vector_type(4))) float ffrag;

#define S_LEN 2048
#define B_DIM 16
#define H_DIM 1024
#define N3H   3072
#define M_DIM 32768  /* S*B */
#define CHUNK 64
#define NCHUNK 32    /* S_LEN / CHUNK */
#define BH    16384  /* B*H */

__device__ __forceinline__ float sigmoidf_(float x) {
  return 1.0f / (1.0f + __expf(-x));
}
__device__ __forceinline__ float tanh_fast(float x) {
  return 2.0f / (1.0f + __expf(-2.0f * x)) - 1.0f;
}

// ---------------- embedding gather: X[s*B+b][h] = bf16(emb[x[s*B+b]][h]) ---
__global__ __launch_bounds__(256) void embed_kernel(
    const int* __restrict__ x, const float* __restrict__ emb,
    bf16_t* __restrict__ X)
{
  const int row = blockIdx.x;            // 0..32767 = s*16+b
  const int v = x[row];
  const float4* src = (const float4*)(emb + (size_t)v * H_DIM);
  float4 f = src[threadIdx.x];
  bf16x4 o;
  o.x = (__bf16)f.x; o.y = (__bf16)f.y; o.z = (__bf16)f.z; o.w = (__bf16)f.w;
  ((bf16x4*)X)[(size_t)row * (H_DIM / 4) + threadIdx.x] = o;
}

// ---------------- weight fp32 -> bf16 --------------------------------------
__global__ __launch_bounds__(256) void cvtw_kernel(
    const float* __restrict__ W, bf16_t* __restrict__ Wb)
{
  const size_t i = (size_t)blockIdx.x * 256 + threadIdx.x;  // float4 index
  float4 f = ((const float4*)W)[i];
  bf16x4 o;
  o.x = (__bf16)f.x; o.y = (__bf16)f.y; o.z = (__bf16)f.z; o.w = (__bf16)f.w;
  ((bf16x4*)Wb)[i] = o;
}

// ---------------- GEMM  Y = act(X * W^T + b) -------------------------------
// R7 = R6 schedule with the steady-state loop ROLLED (#pragma unroll 1) to
// cut code size / compile burden ~4x (two consecutive harness failures on
// the fully-unrolled R6 source; rolled body keeps buffer indices compile-
// time, only the K offset becomes runtime, which global_load_lds accepts).
//
// Schedule: 256x256 tile, 8 waves (2M x 4N), wave-tile 128x64 (acc[8][4],
// ds_read:MFMA = 0.375). BK=32, FOUR LDS buffers (4 x 32K = 128K), ONE
// barrier per phase (32/block), stage 3 tiles ahead with counted vmcnt(4),
// and fragment ds_reads for phase t+1 issued INSIDE phase t's MFMA cluster
// so LDS latency dies in the MFMA/barrier shadow (R5 exposed ~300cy of LDS
// latency per phase; this is the property R3-R5 lacked). Read-ahead reuses
// the same af/bfr registers (dead after their consuming MFMAs; WAR enforced
// by the compiler) -> no VGPR cost.
//
// Slot-lifetime audit (vmcnt retires oldest-first, m135):
//  - read-ahead at iter t reads buf (t+1)&3, staged iter t-2; end-of-(t-1)
//    vmcnt(4) leaves only stage(t+2) outstanding => stage(t+1) landed; the
//    barrier makes that true for ALL waves' staging parts.
//  - stage at iter t writes slot (t+3)&3 = (t-1)&3, whose content (tile t-1)
//    was last ds_read at iter t-2 and consumed before the end-of-(t-1)
//    barrier; stage issues after that barrier. Read slot != stage slot
//    (differ by 2 mod 4).
//  - tail: t=29 waits vmcnt(0) so tile 31 is resident before t=30's
//    read-ahead; t=31 ends with a barrier protecting the epilogue LDS reuse.
// XCD-local supertiling kept from R4 (FETCH 327->183 MB verified): per XCD
// 16m x 12n tiles in 4x3 supertiles -> A 2M + B 2M = 4 MB <= L2.
__global__ __launch_bounds__(512, 2) void gemm_act_kernel(
    const bf16_t* __restrict__ A,
    const bf16_t* __restrict__ Bw,
    const float* __restrict__ bias,
    bf16_t* __restrict__ Y)
{
  constexpr int K = H_DIM;   // 1024 -> 32 K-tiles of 32
  constexpr int N = N3H;     // 3072
  extern __shared__ char lds[] __attribute__((aligned(16)));
  // buf b at b*32768: A 256rows x 64B at +0 (16K), B 256rows x 64B at +16384

  const int tid  = threadIdx.x;
  const int lane = tid & 63;
  const int wave = tid >> 6;     // 0..7
  const int wr = wave >> 2;      // 0..1  M half (128 rows)
  const int wc = wave & 3;       // 0..3  N quarter (64 cols)
  const int fr = lane & 15;
  const int quad = lane >> 4;

  // XCD swizzle + supertile: 1536 blocks = 8 XCDs x 192; per XCD 16m x 12n
  // tiles as 4x3 supertiles of (4m x 4n) = 16 blocks.
  const int bid = blockIdx.x;
  const int xcd = bid & 7;
  const int i   = bid >> 3;            // 0..191 within XCD
  const int st  = i >> 4;              // supertile 0..11
  const int j   = i & 15;              // 0..15 within supertile
  const int m_local = (st / 3) * 4 + (j >> 2);   // 0..15
  const int n_local = (st % 3) * 4 + (j & 3);    // 0..11
  const long m0 = (long)(xcd * 16 + m_local) * 256;
  const long n0 = (long)n_local * 256;

  // staging: thread -> (row = tid>>2 in a 128-row half, chunkpos = tid&3);
  // source chunk pre-swizzled by ((row>>1)&3) == ((tid>>3)&3) so linear LDS
  // dest + swizzled ds_read = involution.
  const int r  = tid >> 2;
  const int sc = ((tid & 3) ^ ((tid >> 3) & 3)) * 8;
  const bf16_t* As0 = A  + (m0 + r) * K + sc;
  const bf16_t* Bs0 = Bw + (n0 + r) * K + sc;
  const int wdst = wave * 1024;  // wave-uniform LDS dest base (+ lane*16 HW)

  // fragment reads: A row = wr*128 + mi*16 + fr, B row = wc*64 + nj*16 + fr,
  // chunkpos = quad ^ ((fr>>1)&3)  (retrieves global k-octet = quad)
  const int cswz = (quad ^ ((fr >> 1) & 3)) * 16;
  const int roffA = (wr * 128 + fr) * 64 + cswz;
  const int roffB = 16384 + (wc * 64 + fr) * 64 + cswz;

  ffrag acc[8][4] = {};
  bfrag af[8], bfr[4];

#define STAGE(sb, ke) do {                                                     \
    __builtin_amdgcn_global_load_lds((AS1 void*)(As0 + (ke)),                  \
        (AS3 void*)(lds + (sb) * 32768 + wdst), 16, 0, 0);                     \
    __builtin_amdgcn_global_load_lds((AS1 void*)(As0 + 128 * K + (ke)),        \
        (AS3 void*)(lds + (sb) * 32768 + 8192 + wdst), 16, 0, 0);              \
    __builtin_amdgcn_global_load_lds((AS1 void*)(Bs0 + (ke)),                  \
        (AS3 void*)(lds + (sb) * 32768 + 16384 + wdst), 16, 0, 0);             \
    __builtin_amdgcn_global_load_lds((AS1 void*)(Bs0 + 128 * K + (ke)),        \
        (AS3 void*)(lds + (sb) * 32768 + 24576 + wdst), 16, 0, 0);             \
  } while (0)
#define RDFRAG(nb) do {                                                        \
    _Pragma("unroll")                                                          \
    for (int mi = 0; mi < 8; ++mi)                                             \
      af[mi] = *(const bfrag*)(lds + (nb) * 32768 + roffA + mi * 1024);        \
    _Pragma("unroll")                                                          \
    for (int nj = 0; nj < 4; ++nj)                                             \
      bfr[nj] = *(const bfrag*)(lds + (nb) * 32768 + roffB + nj * 1024);       \
  } while (0)
#define BARX() do {                                                            \
    __builtin_amdgcn_sched_barrier(0);                                         \
    __builtin_amdgcn_s_barrier();                                              \
    __builtin_amdgcn_sched_barrier(0);                                         \
  } while (0)
// PH: phase with CT = t&3 (compile-time buffer index). MFMA on current regs
// (loaded by previous phase's read-ahead); stage tile t+3 into (CT+3)&3;
// read-ahead buf (CT+1)&3 into the SAME regs. No pin between MFMA and
// read-ahead (interleave wanted).
#define PH(CT, KE, DOSTAGE, DOREAD, VM) do {                                   \
    if (DOSTAGE) STAGE((CT + 3) & 3, KE);                                      \
    __builtin_amdgcn_sched_barrier(0);  /* stage issues before MFMA block */   \
    __builtin_amdgcn_s_setprio(1);                                             \
    _Pragma("unroll")                                                          \
    for (int mi = 0; mi < 8; ++mi)                                             \
      _Pragma("unroll")                                                        \
      for (int nj = 0; nj < 4; ++nj)                                           \
        acc[mi][nj] = __builtin_amdgcn_mfma_f32_16x16x32_bf16(                 \
            af[mi], bfr[nj], acc[mi][nj], 0, 0, 0);                            \
    __builtin_amdgcn_s_setprio(0);                                             \
    if (DOREAD) RDFRAG((CT + 1) & 3);                                          \
    __builtin_amdgcn_sched_barrier(0);                                         \
    if (VM == 1) asm volatile("s_waitcnt vmcnt(4)" ::: "memory");              \
    if (VM == 2) asm volatile("s_waitcnt vmcnt(0)" ::: "memory");              \
    BARX();                                                                    \
  } while (0)

  // prologue: stage tiles 0,1,2 (12 loads/wave); vmcnt(4) -> tiles 0,1
  // landed; barrier (all waves' parts visible); load frags(tile0).
  STAGE(0, 0);
  STAGE(1, 32);
  STAGE(2, 64);
  asm volatile("s_waitcnt vmcnt(4)" ::: "memory");
  BARX();
  RDFRAG(0);

  // steady state rolled: 7 iterations x 4 phases (t = 0..27, staging 3..30).
#pragma unroll 1
  for (int tt = 0; tt < 28; tt += 4) {
    PH(0, (tt + 3) * 32, true, true, 1);
    PH(1, (tt + 4) * 32, true, true, 1);
    PH(2, (tt + 5) * 32, true, true, 1);
    PH(3, (tt + 6) * 32, true, true, 1);
  }
  PH(0, 31 * 32, true,  true,  1);       // t=28: stage tile31; vm4 -> 30 in
  PH(1, 0,       false, true,  2);       // t=29: vm0 -> 31 in for t=30 reads
  PH(2, 0,       false, true,  0);       // t=30: read-ahead buf3 (tile31)
  PH(3, 0,       false, false, 0);       // t=31: consume; barrier protects LDS

  // ---- epilogue: act -> LDS C-tile (256 rows x 512 B, quad-XOR swizzled),
  // then 16 passes of ds_read_b128 -> coalesced 16B stores (verified in R1).
  {
    const int xorv = quad << 5;
#pragma unroll
    for (int nj = 0; nj < 4; ++nj) {
      const long n = n0 + wc * 64 + nj * 16 + fr;
      const float bv = bias[n];
      const bool is_tanh = (n < H_DIM);
      const int colb = (wc * 64 + nj * 16 + fr) * 2;
#pragma unroll
      for (int mi = 0; mi < 8; ++mi) {
        const int row0 = wr * 128 + mi * 16 + quad * 4;
#pragma unroll
        for (int reg = 0; reg < 4; ++reg) {
          const float y = acc[mi][nj][reg] + bv;
          const float a = is_tanh ? tanh_fast(y) : sigmoidf_(y);
          *(bf16_t*)(lds + ((((row0 + reg) * 512) + colb) ^ xorv)) = (bf16_t)a;
        }
      }
    }
    __syncthreads();
#pragma unroll
    for (int p = 0; p < 16; ++p) {
      const int o = p * 8192 + tid * 16;
      const int rr = o >> 9;           // local row
      const int cb = o & 511;          // byte within row
      const float4 v = *(const float4*)(lds + (((rr * 512) + cb) ^ (((rr >> 2) & 3) << 5)));
      *(float4*)((char*)(Y + (size_t)(m0 + rr) * N + n0) + cb) = v;
    }
  }
#undef STAGE
#undef RDFRAG
#undef BARX
#undef PH
}

// ---------------- chunked parallel scan (bf16 Y, 2-wide vectorized) --------
__global__ __launch_bounds__(256) void scan_pass1(
    const bf16_t* __restrict__ Y, float* __restrict__ Ag, float* __restrict__ Dg)
{
  const int idx = blockIdx.x * 256 + threadIdx.x;   // g*8192 + b*512 + h2
  const int g = idx >> 13;
  const int b = (idx >> 9) & 15;
  const int h2 = idx & 511;
  const bf16_t* p = Y + ((size_t)(g * CHUNK * B_DIM + b)) * N3H + h2 * 2;
  float A0 = 1.0f, A1 = 1.0f, c0 = 0.0f, c1 = 0.0f;
  for (int i = 0; i < CHUNK; ++i) {
    const bf16x2 zv = *(const bf16x2*)(p);
    const bf16x2 fv = *(const bf16x2*)(p + H_DIM);
    const float f0 = (float)fv[0], f1 = (float)fv[1];
    const float a0 = 1.0f - f0,    a1 = 1.0f - f1;
    c0 = f0 * (float)zv[0] + a0 * c0;
    c1 = f1 * (float)zv[1] + a1 * c1;
    A0 *= a0;
    A1 *= a1;
    p += (size_t)B_DIM * N3H;
  }
  const int base = g * BH + b * H_DIM + h2 * 2;
  *(float2*)(Ag + base) = make_float2(A0, A1);
  *(float2*)(Dg + base) = make_float2(c0, c1);
}

__global__ __launch_bounds__(256) void scan_pass2(
    const float* __restrict__ Ag, const float* __restrict__ Dg,
    float* __restrict__ Cs)
{
  const int j = blockIdx.x * 256 + threadIdx.x;     // 0..16383
  float c = 0.0f;
#pragma unroll
  for (int g = 0; g < NCHUNK; ++g) {
    Cs[g * BH + j] = c;
    c = Dg[g * BH + j] + Ag[g * BH + j] * c;
  }
}

__global__ __launch_bounds__(256) void scan_pass3(
    const bf16_t* __restrict__ Y, const float* __restrict__ Cs,
    bf16_t* __restrict__ Xn, float* __restrict__ Out, const int last)
{
  const int idx = blockIdx.x * 256 + threadIdx.x;   // g*8192 + b*512 + h2
  const int g = idx >> 13;
  const int b = (idx >> 9) & 15;
  const int h2 = idx & 511;
  const bf16_t* p = Y + ((size_t)(g * CHUNK * B_DIM + b)) * N3H + h2 * 2;
  const int cb = g * BH + b * H_DIM + h2 * 2;
  float c0 = Cs[cb], c1 = Cs[cb + 1];
  size_t oo = (size_t)g * CHUNK * BH + (size_t)b * H_DIM + h2 * 2;
  for (int i = 0; i < CHUNK; ++i) {
    const bf16x2 zv = *(const bf16x2*)(p);
    const bf16x2 fv = *(const bf16x2*)(p + H_DIM);
    const bf16x2 ov = *(const bf16x2*)(p + 2 * H_DIM);
    const float f0 = (float)fv[0], f1 = (float)fv[1];
    c0 = f0 * (float)zv[0] + (1.0f - f0) * c0;
    c1 = f1 * (float)zv[1] + (1.0f - f1) * c1;
    const float v0 = (float)ov[0] * c0;
    const float v1 = (float)ov[1] * c1;
    if (last) {
      const int s = g * CHUNK + i;
      if (s < S_LEN - 1) *(float2*)(Out + oo) = make_float2(v0, v1);  // out = X[:-1]
    } else {
      bf16x2 w; w[0] = (__bf16)v0; w[1] = (__bf16)v1;
      *(bf16x2*)(Xn + oo) = w;
    }
    p += (size_t)B_DIM * N3H;
    oo += (size_t)BH;
  }
}

extern "C" void kernel_launch(void* const* d_in, const int* in_sizes, int n_in,
                              void* d_out, int out_size, void* d_ws, size_t ws_size,
                              hipStream_t stream)
{
  const int*   x   = (const int*)d_in[0];
  const float* emb = (const float*)d_in[1];
  const float* W[3]  = {(const float*)d_in[2], (const float*)d_in[4], (const float*)d_in[6]};
  const float* bv[3] = {(const float*)d_in[3], (const float*)d_in[5], (const float*)d_in[7]};
  float* out = (float*)d_out;

  char* ws = (char*)d_ws;
  bf16_t* Xbf = (bf16_t*)ws;                                // 67,108,864 B
  bf16_t* Wbf = (bf16_t*)(ws + 67108864);                   //  6,291,456 B
  bf16_t* Yb  = (bf16_t*)(ws + 67108864 + 6291456);         // 201,326,592 B
  char* tail  = ws + 67108864 + 6291456 + 201326592;
  float* Ag = (float*)tail;                                 // 2,097,152 B
  float* Dg = (float*)(tail + 2097152);                     // 2,097,152 B
  float* Cs = (float*)(tail + 4194304);                     // 2,097,152 B
  (void)ws_size;

  // 128 KiB dynamic LDS opt-in; host-side API, graph-capture safe.
  hipFuncSetAttribute((const void*)gemm_act_kernel,
                      hipFuncAttributeMaxDynamicSharedMemorySize, 131072);

  embed_kernel<<<M_DIM, 256, 0, stream>>>(x, emb, Xbf);

  for (int l = 0; l < 3; ++l) {
    const int last = (l == 2);
    cvtw_kernel<<<3072, 256, 0, stream>>>(W[l], Wbf);
    gemm_act_kernel<<<1536, 512, 131072, stream>>>(Xbf, Wbf, bv[l], Yb);
    scan_pass1<<<1024, 256, 0, stream>>>(Yb, Ag, Dg);
    scan_pass2<<<64, 256, 0, stream>>>(Ag, Dg, Cs);
    scan_pass3<<<1024, 256, 0, stream>>>(Yb, Cs, Xbf, out, last);
  }
}